// Round 1
// baseline (120.906 us; speedup 1.0000x reference)
//
#include <hip/hip_runtime.h>
#include <hip/hip_bf16.h>

#define NN 8192
#define INF_ 256
#define OUTF 64
#define ALPHA 0.2f
#define LOG2E 1.44269504088896f

typedef __attribute__((ext_vector_type(8))) short short8;
typedef __attribute__((ext_vector_type(4))) float f32x4;

static __device__ __forceinline__ unsigned short f2bf(float f) {
  unsigned u = __builtin_bit_cast(unsigned, f);
  u += 0x7fffu + ((u >> 16) & 1u);          // RNE; inputs are finite
  return (unsigned short)(u >> 16);
}

static __device__ __forceinline__ float pval(int a, float s2v, float s1v, float msc) {
  const float x = s1v + s2v;
  const float lr = fmaxf(x, ALPHA * x);      // leaky_relu, alpha<1
  const float e = exp2f(fmaf(lr, LOG2E, -msc));
  return a > 0 ? e : 0.f;
}

static __device__ __forceinline__ ushort4 p4(const int4 a, const float4 s,
                                             float s1v, float msc, float& lp) {
  const float p0 = pval(a.x, s.x, s1v, msc);
  const float p1 = pval(a.y, s.y, s1v, msc);
  const float p2 = pval(a.z, s.z, s1v, msc);
  const float p3 = pval(a.w, s.w, s1v, msc);
  lp += (p0 + p1) + (p2 + p3);
  ushort4 r;
  r.x = f2bf(p0); r.y = f2bf(p1); r.z = f2bf(p2); r.w = f2bf(p3);
  return r;
}

// ---------------- Kernel A: h' = X@W  ->  hp_t (bf16, transposed), s1, s2, per-block s2max
__global__ __launch_bounds__(256) void k_prep(
    const float* __restrict__ X, const float* __restrict__ W,
    const float* __restrict__ a1, const float* __restrict__ a2,
    unsigned short* __restrict__ hpt, float* __restrict__ s1,
    float* __restrict__ s2, float* __restrict__ pmax)
{
  __shared__ float Ws[INF_ * OUTF];   // 64 KB
  __shared__ float Xs[32 * INF_];     // 32 KB
  __shared__ float sm8[8];
  const int t = threadIdx.x;
  const int ib = blockIdx.x;

  #pragma unroll
  for (int i = 0; i < 16; ++i) {
    const int idx = (i * 256 + t) * 4;
    *reinterpret_cast<float4*>(&Ws[idx]) = *reinterpret_cast<const float4*>(&W[idx]);
  }
  const float* Xb = X + (size_t)ib * 32 * INF_;
  #pragma unroll
  for (int i = 0; i < 8; ++i) {
    const int idx = (i * 256 + t) * 4;
    *reinterpret_cast<float4*>(&Xs[idx]) = *reinterpret_cast<const float4*>(&Xb[idx]);
  }
  __syncthreads();

  const int rg = t >> 5;          // 0..7 -> rows 4*rg..4*rg+3
  const int r0 = rg * 4;
  const int c0 = 2 * (t & 31);    // 2 consecutive output features
  float acc[4][2] = {{0.f,0.f},{0.f,0.f},{0.f,0.f},{0.f,0.f}};

  for (int k = 0; k < INF_; k += 4) {
    float xv[4][4];
    #pragma unroll
    for (int rr = 0; rr < 4; ++rr)
      *reinterpret_cast<float4*>(&xv[rr][0]) =
          *reinterpret_cast<const float4*>(&Xs[(r0 + rr) * INF_ + k]);
    #pragma unroll
    for (int kk = 0; kk < 4; ++kk) {
      const float2 wv = *reinterpret_cast<const float2*>(&Ws[(k + kk) * OUTF + c0]);
      #pragma unroll
      for (int rr = 0; rr < 4; ++rr) {
        acc[rr][0] = fmaf(xv[rr][kk], wv.x, acc[rr][0]);
        acc[rr][1] = fmaf(xv[rr][kk], wv.y, acc[rr][1]);
      }
    }
  }

  // s1/s2 partials from f32 accumulators
  const float a10 = a1[c0], a11 = a1[c0 + 1];
  const float a20 = a2[c0], a21 = a2[c0 + 1];
  float sp1[4], sp2[4];
  #pragma unroll
  for (int rr = 0; rr < 4; ++rr) {
    sp1[rr] = acc[rr][0] * a10 + acc[rr][1] * a11;
    sp2[rr] = acc[rr][0] * a20 + acc[rr][1] * a21;
  }
  #pragma unroll
  for (int d = 1; d < 32; d <<= 1) {
    #pragma unroll
    for (int rr = 0; rr < 4; ++rr) {
      sp1[rr] += __shfl_xor(sp1[rr], d, 64);
      sp2[rr] += __shfl_xor(sp2[rr], d, 64);
    }
  }

  // hp_t[f][node] bf16 — thread owns 4 consecutive rows -> 8B stores
  const int gr = ib * 32 + r0;
  #pragma unroll
  for (int cc = 0; cc < 2; ++cc) {
    ushort4 pk;
    pk.x = f2bf(acc[0][cc]); pk.y = f2bf(acc[1][cc]);
    pk.z = f2bf(acc[2][cc]); pk.w = f2bf(acc[3][cc]);
    *reinterpret_cast<ushort4*>(&hpt[(size_t)(c0 + cc) * NN + gr]) = pk;
  }
  if ((t & 31) == 0) {
    #pragma unroll
    for (int rr = 0; rr < 4; ++rr) { s1[gr + rr] = sp1[rr]; s2[gr + rr] = sp2[rr]; }
    sm8[rg] = fmaxf(fmaxf(sp2[0], sp2[1]), fmaxf(sp2[2], sp2[3]));
  }
  __syncthreads();
  if (t == 0) {
    float m = sm8[0];
    #pragma unroll
    for (int i = 1; i < 8; ++i) m = fmaxf(m, sm8[i]);
    pmax[ib] = m;
  }
}

// ---------------- Kernel R: global max of s2
__global__ void k_rmax(const float* __restrict__ pmax, float* __restrict__ s2max) {
  const int t = threadIdx.x;  // 64 threads
  float m = fmaxf(fmaxf(pmax[t], pmax[t + 64]), fmaxf(pmax[t + 128], pmax[t + 192]));
  #pragma unroll
  for (int d = 1; d < 64; d <<= 1) m = fmaxf(m, __shfl_xor(m, d, 64));
  if (t == 0) *s2max = m;
}

// ---------------- Kernel C: fused masked-softmax + attn@h' + elu
// 256 blocks x 512 threads; block owns 32 rows; 8 waves = 2(M) x 4(N) over 32x64 output.
__global__ __launch_bounds__(512) void k_main(
    const int* __restrict__ adj, const unsigned short* __restrict__ hpt,
    const float* __restrict__ s1g, const float* __restrict__ s2g,
    const float* __restrict__ s2max, float* __restrict__ out)
{
  __shared__ unsigned short Pl[2][32][136];  // pad 128->136: 272B row stride, conflict-free b128 reads
  __shared__ float l_sh[32];
  const int t = threadIdx.x;
  const int ib = blockIdx.x;
  const int lane = t & 63;
  const int w = t >> 6;
  const int wm = w & 1;        // M half (16 rows)
  const int wn = w >> 1;       // N slice (16 cols)
  const int row_p = t >> 4;    // 0..31: P-compute row
  const int cp = t & 15;       // P-compute col group
  const size_t arow = (size_t)(ib * 32 + row_p) * NN;
  const float s1v = s1g[ib * 32 + row_p];
  const float SM = *s2max;
  const float xm = s1v + SM;
  const float msc = fmaxf(xm, ALPHA * xm) * LOG2E;   // M_i * log2(e), M_i >= row max (lrelu monotone)
  const unsigned short* hb = hpt + (size_t)(wn * 16 + (lane & 15)) * NN + ((lane >> 4) * 8);
  const unsigned short* Pr0 = &Pl[0][wm * 16 + (lane & 15)][(lane >> 4) * 8];
  float lpart = 0.f;
  f32x4 acc = {0.f, 0.f, 0.f, 0.f};

  // ---- prologue: tile 0 ----
  int4 ajA = *reinterpret_cast<const int4*>(adj + arow + 4 * cp);
  int4 ajB = *reinterpret_cast<const int4*>(adj + arow + 64 + 4 * cp);
  int4 naA = *reinterpret_cast<const int4*>(adj + arow + 128 + 4 * cp);
  int4 naB = *reinterpret_cast<const int4*>(adj + arow + 192 + 4 * cp);
  short8 bfr[4];
  #pragma unroll
  for (int s = 0; s < 4; ++s)
    bfr[s] = *reinterpret_cast<const short8*>(hb + 32 * s);
  {
    const float4 s2a = *reinterpret_cast<const float4*>(s2g + 4 * cp);
    const float4 s2b = *reinterpret_cast<const float4*>(s2g + 64 + 4 * cp);
    const ushort4 pw0 = p4(ajA, s2a, s1v, msc, lpart);
    const ushort4 pw1 = p4(ajB, s2b, s1v, msc, lpart);
    *reinterpret_cast<ushort4*>(&Pl[0][row_p][4 * cp]) = pw0;
    *reinterpret_cast<ushort4*>(&Pl[0][row_p][64 + 4 * cp]) = pw1;
  }
  __syncthreads();

  // ---- pipelined main loop: segment = MFMA(t-1) | prefetch adj(t+1) | load B(t) | P(t) ----
  for (int tile = 1; tile < 64; ++tile) {
    const int j0 = tile << 7;
    {
      const unsigned short* Pr = Pr0 + ((tile - 1) & 1) * (32 * 136);
      #pragma unroll
      for (int s = 0; s < 4; ++s) {
        const short8 af = *reinterpret_cast<const short8*>(Pr + 32 * s);
        acc = __builtin_amdgcn_mfma_f32_16x16x32_bf16(af, bfr[s], acc, 0, 0, 0);
      }
    }
    ajA = naA; ajB = naB;
    const int jn = (tile < 63) ? (j0 + 128) : 0;   // tail reloads tile0 (discarded)
    naA = *reinterpret_cast<const int4*>(adj + arow + jn + 4 * cp);
    naB = *reinterpret_cast<const int4*>(adj + arow + jn + 64 + 4 * cp);
    #pragma unroll
    for (int s = 0; s < 4; ++s)
      bfr[s] = *reinterpret_cast<const short8*>(hb + j0 + 32 * s);
    {
      const float4 s2a = *reinterpret_cast<const float4*>(s2g + j0 + 4 * cp);
      const float4 s2b = *reinterpret_cast<const float4*>(s2g + j0 + 64 + 4 * cp);
      const ushort4 pw0 = p4(ajA, s2a, s1v, msc, lpart);
      const ushort4 pw1 = p4(ajB, s2b, s1v, msc, lpart);
      *reinterpret_cast<ushort4*>(&Pl[tile & 1][row_p][4 * cp]) = pw0;
      *reinterpret_cast<ushort4*>(&Pl[tile & 1][row_p][64 + 4 * cp]) = pw1;
    }
    __syncthreads();
  }
  // ---- epilogue MFMA (tile 63) ----
  {
    const unsigned short* Pr = Pr0 + (63 & 1) * (32 * 136);
    #pragma unroll
    for (int s = 0; s < 4; ++s) {
      const short8 af = *reinterpret_cast<const short8*>(Pr + 32 * s);
      acc = __builtin_amdgcn_mfma_f32_16x16x32_bf16(af, bfr[s], acc, 0, 0, 0);
    }
  }

  // denominator: 16 threads share a row (consecutive lanes)
  lpart += __shfl_xor(lpart, 1, 64);
  lpart += __shfl_xor(lpart, 2, 64);
  lpart += __shfl_xor(lpart, 4, 64);
  lpart += __shfl_xor(lpart, 8, 64);
  if (cp == 0) l_sh[row_p] = lpart;
  __syncthreads();

  // C/D layout (m89): col = lane&15, row = (lane>>4)*4 + reg
  const int ocol = wn * 16 + (lane & 15);
  #pragma unroll
  for (int r = 0; r < 4; ++r) {
    const int orow = wm * 16 + (lane >> 4) * 4 + r;
    const float dv = acc[r] / l_sh[orow];
    const float res = dv > 0.f ? dv : (expf(dv) - 1.f);   // elu
    out[(size_t)(ib * 32 + orow) * OUTF + ocol] = res;
  }
}

extern "C" void kernel_launch(void* const* d_in, const int* in_sizes, int n_in,
                              void* d_out, int out_size, void* d_ws, size_t ws_size,
                              hipStream_t stream) {
  (void)in_sizes; (void)n_in; (void)out_size; (void)ws_size;
  const float* X  = (const float*)d_in[0];
  const int* adj  = (const int*)d_in[1];
  const float* W  = (const float*)d_in[2];
  const float* a1 = (const float*)d_in[3];
  const float* a2 = (const float*)d_in[4];
  float* out = (float*)d_out;

  char* ws = (char*)d_ws;
  unsigned short* hpt = (unsigned short*)ws;                    // 64*8192*2 = 1 MB
  float* s1   = (float*)(ws + (size_t)OUTF * NN * 2);           // 32 KB
  float* s2   = s1 + NN;                                        // 32 KB
  float* pmax = s2 + NN;                                        // 1 KB
  float* s2m  = pmax + 256;                                     // 4 B

  hipLaunchKernelGGL(k_prep, dim3(256), dim3(256), 0, stream, X, W, a1, a2, hpt, s1, s2, pmax);
  hipLaunchKernelGGL(k_rmax, dim3(1), dim3(64), 0, stream, pmax, s2m);
  hipLaunchKernelGGL(k_main, dim3(256), dim3(512), 0, stream, adj, hpt, s1, s2, s2m, out);
}